// Round 1
// baseline (832.155 us; speedup 1.0000x reference)
//
#include <hip/hip_runtime.h>
#include <cstddef>

// LSTM: T=2048, B=2048, I=1, H=20. Gates concat [f,i,o,c] along dim0 of W/U.
// Outputs: h_seq (T,B,H) ++ h_last (B,H) ++ c_last (B,H), fp32.
//
// Layout: thread = (batch, j). Each thread owns c[j], computes z_f,z_i,z_o,z_c
// for its j (4 U-rows in registers), updates c/h, broadcasts h via LDS.
// Block = 160 threads = 8 batches; grid = 256 blocks = 1 per CU.
// One __syncthreads per step via double-buffered h_lds.

constexpr int T = 2048;
constexpr int B = 2048;
constexpr int H = 20;
constexpr int BPB = 8;              // batches per block
constexpr int THREADS = BPB * H;    // 160

__device__ __forceinline__ float fast_rcp(float x) {
    return __builtin_amdgcn_rcpf(x);
}
__device__ __forceinline__ float sigmoid_f(float x) {
    // 1/(1+e^{-x}); x->+inf: 1, x->-inf: rcp(inf)=0. Stable.
    return fast_rcp(1.0f + __expf(-x));
}
__device__ __forceinline__ float tanh_f(float x) {
    // 1 - 2/(e^{2x}+1); x->+inf: 1-0=1, x->-inf: 1-2=-1. Stable.
    return 1.0f - 2.0f * fast_rcp(__expf(2.0f * x) + 1.0f);
}

__global__ __launch_bounds__(THREADS, 1)
void lstm_fused(const float* __restrict__ x,   // (T,B) since I==1
                const float* __restrict__ W,   // (80,1)
                const float* __restrict__ U,   // (80,20) row-major
                const float* __restrict__ bw,  // (80,)
                const float* __restrict__ bu,  // (80,)
                float* __restrict__ out) {
    __shared__ float h_lds[2][BPB][H];

    const int tid = threadIdx.x;
    const int bl  = tid / H;          // batch within block [0,8)
    const int j   = tid % H;          // hidden unit [0,20)
    const int bg  = blockIdx.x * BPB + bl;

    // Preload the 4 U-rows (gate q, hidden j), W and combined bias into regs.
    float Ur[4][H];
    float Wr[4], br[4];
#pragma unroll
    for (int q = 0; q < 4; ++q) {
        const int g = q * H + j;
        Wr[q] = W[g];                 // I == 1 -> W is a column vector
        br[q] = bw[g] + bu[g];
#pragma unroll
        for (int k = 0; k < H; ++k) Ur[q][k] = U[g * H + k];
    }

    h_lds[0][bl][j] = 0.0f;
    float c = 0.0f;
    __syncthreads();

    // Software-pipeline x loads 2 steps ahead (hide HBM latency).
    float xv  = x[0 * B + bg];
    float xn1 = x[1 * B + bg];

    for (int t = 0; t < T; ++t) {
        const float xn2 = (t + 2 < T) ? x[(t + 2) * B + bg] : 0.0f;
        const int rb = t & 1;
        const int wb = rb ^ 1;

        // Broadcast-read the 8-batch group's h vector (20 floats, 5x float4).
        float h[H];
        const float4* hp = reinterpret_cast<const float4*>(&h_lds[rb][bl][0]);
#pragma unroll
        for (int k4 = 0; k4 < H / 4; ++k4) {
            const float4 v = hp[k4];
            h[4 * k4 + 0] = v.x; h[4 * k4 + 1] = v.y;
            h[4 * k4 + 2] = v.z; h[4 * k4 + 3] = v.w;
        }

        float z0 = fmaf(xv, Wr[0], br[0]);
        float z1 = fmaf(xv, Wr[1], br[1]);
        float z2 = fmaf(xv, Wr[2], br[2]);
        float z3 = fmaf(xv, Wr[3], br[3]);
#pragma unroll
        for (int k = 0; k < H; ++k) {
            z0 = fmaf(Ur[0][k], h[k], z0);
            z1 = fmaf(Ur[1][k], h[k], z1);
            z2 = fmaf(Ur[2][k], h[k], z2);
            z3 = fmaf(Ur[3][k], h[k], z3);
        }

        const float f  = sigmoid_f(z0);
        const float i  = sigmoid_f(z1);
        const float o  = sigmoid_f(z2);
        const float gt = tanh_f(z3);
        c = fmaf(f, c, i * gt);
        const float hnew = o * tanh_f(c);

        h_lds[wb][bl][j] = hnew;
        out[(size_t)t * (B * H) + (size_t)bg * H + j] = hnew;

        if (t == T - 1) {
            out[(size_t)T * (B * H) + (size_t)bg * H + j] = hnew;              // h_last
            out[(size_t)T * (B * H) + (size_t)B * H + (size_t)bg * H + j] = c; // c_last
        }

        xv = xn1; xn1 = xn2;
        __syncthreads();
    }
}

extern "C" void kernel_launch(void* const* d_in, const int* in_sizes, int n_in,
                              void* d_out, int out_size, void* d_ws, size_t ws_size,
                              hipStream_t stream) {
    (void)in_sizes; (void)n_in; (void)d_ws; (void)ws_size; (void)out_size;
    const float* x  = (const float*)d_in[0];
    const float* W  = (const float*)d_in[1];
    const float* U  = (const float*)d_in[2];
    const float* bw = (const float*)d_in[3];
    const float* bu = (const float*)d_in[4];
    float* out = (float*)d_out;

    lstm_fused<<<dim3(B / BPB), dim3(THREADS), 0, stream>>>(x, W, U, bw, bu, out);
}

// Round 2
// 505.669 us; speedup vs baseline: 1.6457x; 1.6457x over previous
//
#include <hip/hip_runtime.h>
#include <cstddef>

// LSTM T=2048, B=2048, I=1, H=20. Gates [f,i,o,c] rows of W/U.
// Wave-synchronous design: block = 1 wave (64 threads) = 3 batches x 20 units
// (lanes 60..63 dummy). NO __syncthreads anywhere -> the per-step global store
// of h is never drained by a pre-barrier s_waitcnt vmcnt(0); only lgkmcnt
// (LDS) ordering is on the critical path.
// x is staged through LDS in 20-step chunks, prefetched one chunk ahead, so
// the steady-state step loop contains no global loads.
// Gate math packed as float2 -> v_pk_fma_f32 (2 chains of 21 instead of 4).

constexpr int T = 2048;
constexpr int B = 2048;
constexpr int H = 20;
constexpr int BPW = 3;      // batches per wave (lanes 0..59)
constexpr int SLOTS = 4;    // 3 real + 1 dummy slot for lanes 60..63
constexpr int CHUNK = 20;   // x staging chunk (lane j loads step t0+j)

typedef float f2 __attribute__((ext_vector_type(2)));

__device__ __forceinline__ float fast_rcp(float x) { return __builtin_amdgcn_rcpf(x); }
__device__ __forceinline__ float sigmoid_f(float x) {
    return fast_rcp(1.0f + __expf(-x));          // stable at +-inf
}
__device__ __forceinline__ float tanh_f(float x) {
    return 1.0f - 2.0f * fast_rcp(__expf(2.0f * x) + 1.0f);  // stable at +-inf
}

__global__ __launch_bounds__(64, 1)
void lstm_wave(const float* __restrict__ x,   // (T,B)
               const float* __restrict__ W,   // (80,)
               const float* __restrict__ U,   // (80,20)
               const float* __restrict__ bw,  // (80,)
               const float* __restrict__ bu,  // (80,)
               float* __restrict__ out) {
    __shared__ float h_lds[2][SLOTS][CHUNK];   // [step parity][slot][j]
    __shared__ float x_lds[2][SLOTS][CHUNK];   // [chunk parity][slot][s]

    const int tid = threadIdx.x;               // 0..63
    const int bl  = tid / H;                   // 0..3 (3 = dummy)
    const int j   = tid % H;
    const int bg  = blockIdx.x * BPW + bl;
    const bool valid = (bl < BPW) && (bg < B);

    // Per-thread gate rows: (f,i) packed, (o,c) packed.
    f2 w01, w23, b01, b23;
    w01.x = W[0 * H + j]; w01.y = W[1 * H + j];
    w23.x = W[2 * H + j]; w23.y = W[3 * H + j];
    b01.x = bw[0 * H + j] + bu[0 * H + j];
    b01.y = bw[1 * H + j] + bu[1 * H + j];
    b23.x = bw[2 * H + j] + bu[2 * H + j];
    b23.y = bw[3 * H + j] + bu[3 * H + j];

    f2 u01[H], u23[H];
#pragma unroll
    for (int k = 0; k < H; ++k) {
        u01[k].x = U[(0 * H + j) * H + k];
        u01[k].y = U[(1 * H + j) * H + k];
        u23[k].x = U[(2 * H + j) * H + k];
        u23[k].y = U[(3 * H + j) * H + k];
    }

    h_lds[0][bl][j] = 0.0f;
    float c = 0.0f;

    // Chunk 0 of x into x_lds[0]; prefetch chunk 1 into a register.
    float xr = valid ? x[(size_t)j * B + bg] : 0.0f;
    x_lds[0][bl][j] = xr;
    float xnext = (valid && (CHUNK + j) < T) ? x[(size_t)(CHUNK + j) * B + bg] : 0.0f;

#define STEP(tt, PAR)                                                          \
    {                                                                          \
        __builtin_amdgcn_wave_barrier(); /* pin DS order, no runtime cost */   \
        float hb[H];                                                           \
        const float4* hp = reinterpret_cast<const float4*>(&h_lds[PAR][bl][0]);\
        _Pragma("unroll")                                                      \
        for (int k4 = 0; k4 < H / 4; ++k4) {                                   \
            const float4 v = hp[k4];                                           \
            hb[4 * k4 + 0] = v.x; hb[4 * k4 + 1] = v.y;                        \
            hb[4 * k4 + 2] = v.z; hb[4 * k4 + 3] = v.w;                        \
        }                                                                      \
        const float xv = x_lds[cb][bl][(tt) - t0];                             \
        f2 z01 = w01 * xv + b01;                                               \
        f2 z23 = w23 * xv + b23;                                               \
        _Pragma("unroll")                                                      \
        for (int k = 0; k < H; ++k) {                                          \
            f2 hk; hk.x = hb[k]; hk.y = hb[k];                                 \
            z01 = u01[k] * hk + z01;                                           \
            z23 = u23[k] * hk + z23;                                           \
        }                                                                      \
        const float fg = sigmoid_f(z01.x);                                     \
        const float ig = sigmoid_f(z01.y);                                     \
        const float og = sigmoid_f(z23.x);                                     \
        const float gg = tanh_f(z23.y);                                        \
        c = fmaf(fg, c, ig * gg);                                              \
        const float hn = og * tanh_f(c);                                       \
        h_lds[(PAR) ^ 1][bl][j] = hn;                                          \
        if (valid) {                                                           \
            out[((size_t)(tt) * B + bg) * H + j] = hn;                         \
            if ((tt) == T - 1) {                                               \
                out[(size_t)T * B * H + (size_t)bg * H + j] = hn;              \
                out[(size_t)T * B * H + (size_t)B * H + (size_t)bg * H + j] = c;\
            }                                                                  \
        }                                                                      \
    }

    const int nch = (T + CHUNK - 1) / CHUNK;   // 103 (last chunk = 8 steps)
    for (int ch = 0; ch < nch; ++ch) {
        const int t0 = ch * CHUNK;
        const int cb = ch & 1;
        const int nsteps = (T - t0 < CHUNK) ? (T - t0) : CHUNK;  // 20 or 8, even
        for (int s = 0; s < nsteps; s += 2) {
            STEP(t0 + s, 0)
            STEP(t0 + s + 1, 1)
        }
        if (ch + 1 < nch) {
            // Stage next chunk (loaded a chunk ago), prefetch chunk+2.
            x_lds[cb ^ 1][bl][j] = xnext;
            const int tpre = t0 + 2 * CHUNK + j;
            xnext = (valid && tpre < T) ? x[(size_t)tpre * B + bg] : 0.0f;
        }
    }
#undef STEP
}

extern "C" void kernel_launch(void* const* d_in, const int* in_sizes, int n_in,
                              void* d_out, int out_size, void* d_ws, size_t ws_size,
                              hipStream_t stream) {
    (void)in_sizes; (void)n_in; (void)d_ws; (void)ws_size; (void)out_size;
    const float* x  = (const float*)d_in[0];
    const float* W  = (const float*)d_in[1];
    const float* U  = (const float*)d_in[2];
    const float* bw = (const float*)d_in[3];
    const float* bu = (const float*)d_in[4];
    float* out = (float*)d_out;

    const int grid = (B + BPW - 1) / BPW;      // 683 one-wave blocks
    lstm_wave<<<dim3(grid), dim3(64), 0, stream>>>(x, W, U, bw, bu, out);
}

// Round 4
// 482.765 us; speedup vs baseline: 1.7237x; 1.0474x over previous
//
#include <hip/hip_runtime.h>
#include <cstddef>

// LSTM T=2048, B=2048, I=1, H=20; gates [f,i,o,c] rows of W/U.
// Latency-bound: time = T x per-step chain L. Round-2-proven exchange
// discipline (double-buffered h_lds + wave_barrier each step) + register-only
// compute cuts:
//  - packed f2 gate math -> v_pk_fma_f32 (42 FMA-issues/step instead of 84)
//  - tree-split chains (dep depth 21 -> 11)
//  - weights pre-scaled by -log2e (f,i,o) / +2log2e (c): acts = rcp(1+exp2(z))
//  - next-step x read issued one step early; x-term folded in last
//  - CHUNK=16 (128 exact chunks), full unroll, compile-time parity

constexpr int T = 2048;
constexpr int B = 2048;
constexpr int H = 20;
constexpr int BPW = 3;               // batches per wave (lanes 0..59)
constexpr int SLOTS = 4;             // 3 real + 1 dummy lane group
constexpr int CHUNK = 16;
constexpr int NCH = T / CHUNK;       // 128 exact

typedef float f2 __attribute__((ext_vector_type(2)));

__device__ __forceinline__ float rcp_f(float v) { return __builtin_amdgcn_rcpf(v); }
__device__ __forceinline__ float ex2(float v)   { return __builtin_amdgcn_exp2f(v); }

__global__ __launch_bounds__(64, 1)
void lstm_wave4(const float* __restrict__ xg, const float* __restrict__ Wg,
                const float* __restrict__ Ug, const float* __restrict__ bwg,
                const float* __restrict__ bug, float* __restrict__ out) {
  __shared__ float h_lds[2][SLOTS][H];        // double-buffered h exchange
  __shared__ float x_lds[2][SLOTS][CHUNK];    // double-buffered x staging

  const int tid = threadIdx.x;
  const int bl  = tid / H;                    // 0..3 (3 = dummy group)
  const int j   = tid % H;                    // hidden unit
  const int bg0 = blockIdx.x * BPW + bl;
  const bool st = (bl < BPW) && (bg0 < B);    // lane stores results
  const int bgi = (bg0 < B) ? bg0 : (B - 1);  // clamped batch for loads

  constexpr float K1 = 1.44269504f;           // log2(e)

  // Packed per-thread gate rows: (f,i) and (o,c), pre-scaled.
  f2 u01[H], u23[H], w01, w23, b01, b23;
#pragma unroll
  for (int k = 0; k < H; ++k) {
    u01[k].x = Ug[(0 * H + j) * H + k] * (-K1);
    u01[k].y = Ug[(1 * H + j) * H + k] * (-K1);
    u23[k].x = Ug[(2 * H + j) * H + k] * (-K1);
    u23[k].y = Ug[(3 * H + j) * H + k] * (2.0f * K1);
  }
  w01.x = Wg[0 * H + j] * (-K1);      w01.y = Wg[1 * H + j] * (-K1);
  w23.x = Wg[2 * H + j] * (-K1);      w23.y = Wg[3 * H + j] * (2.0f * K1);
  b01.x = (bwg[0 * H + j] + bug[0 * H + j]) * (-K1);
  b01.y = (bwg[1 * H + j] + bug[1 * H + j]) * (-K1);
  b23.x = (bwg[2 * H + j] + bug[2 * H + j]) * (-K1);
  b23.y = (bwg[3 * H + j] + bug[3 * H + j]) * (2.0f * K1);

  // Zero-init ALL LDS we ever read (incl. dummy-group tails): deterministic.
  for (int q = tid; q < 2 * SLOTS * H;     q += 64) (&h_lds[0][0][0])[q] = 0.f;
  for (int q = tid; q < 2 * SLOTS * CHUNK; q += 64) (&x_lds[0][0][0])[q] = 0.f;
  __builtin_amdgcn_wave_barrier();

  // Stage x chunk 0; prefetch chunk 1 into a register.
  if (j < CHUNK) x_lds[0][bl][j] = xg[(size_t)j * B + bgi];
  float xnext = (j < CHUNK) ? xg[(size_t)(CHUNK + j) * B + bgi] : 0.f;
  __builtin_amdgcn_wave_barrier();

  float c = 0.f, hn = 0.f;
  float xv = x_lds[0][bl][0];

  float* outp = out + (size_t)bgi * H + j;
  constexpr size_t OSTRIDE = (size_t)B * H;

  for (int ch = 0; ch < NCH; ++ch) {
    const int cb = ch & 1;
    // Stage chunk ch+1 (held in xnext); prefetch chunk ch+2.
    if (j < CHUNK) {
      x_lds[cb ^ 1][bl][j] = xnext;
      const int tp = (ch + 2) * CHUNK + j;
      xnext = (tp < T) ? xg[(size_t)tp * B + bgi] : 0.f;
    }
#pragma unroll
    for (int s = 0; s < CHUNK; ++s) {
      const int p = s & 1;                    // compile-time after unroll
      __builtin_amdgcn_wave_barrier();        // pin DS schedule (free)
      // h broadcast: 5x ds_read_b128, conflict-free (4 bases, disjoint banks).
      const float4* hp4 = reinterpret_cast<const float4*>(&h_lds[p][bl][0]);
      const float4 v0 = hp4[0], v1 = hp4[1], v2 = hp4[2], v3 = hp4[3], v4 = hp4[4];
      const float hb[H] = {v0.x, v0.y, v0.z, v0.w, v1.x, v1.y, v1.z, v1.w,
                           v2.x, v2.y, v2.z, v2.w, v3.x, v3.y, v3.z, v3.w,
                           v4.x, v4.y, v4.z, v4.w};
      // Next step's x, issued early (off the h critical path).
      const float xnv = (s + 1 < CHUNK) ? x_lds[cb][bl][s + 1]
                                        : x_lds[cb ^ 1][bl][0];
      // Packed tree-split dots: 2x (depth-11 + depth-10) v_pk_fma chains.
      f2 za01 = b01, za23 = b23;
      f2 zb01 = u01[10] * hb[10], zb23 = u23[10] * hb[10];
#pragma unroll
      for (int k = 0; k < 10; ++k) {
        za01 = u01[k] * hb[k] + za01;
        za23 = u23[k] * hb[k] + za23;
      }
#pragma unroll
      for (int k = 11; k < H; ++k) {
        zb01 = u01[k] * hb[k] + zb01;
        zb23 = u23[k] * hb[k] + zb23;
      }
      f2 xv2; xv2.x = xv; xv2.y = xv;
      const f2 z01 = w01 * xv2 + (za01 + zb01);
      const f2 z23 = w23 * xv2 + (za23 + zb23);
      // Activations (pre-scaled): no muls on the chain.
      const float fg = rcp_f(1.f + ex2(z01.x));
      const float ig = rcp_f(1.f + ex2(z01.y));
      const float og = rcp_f(1.f + ex2(z23.x));
      const float gt = fmaf(-2.f, rcp_f(1.f + ex2(z23.y)), 1.f);
      c = fmaf(fg, c, ig * gt);
      const float th = fmaf(-2.f, rcp_f(1.f + ex2(c * (2.f * K1))), 1.f);
      hn = og * th;
      h_lds[p ^ 1][bl][j] = hn;               // write the OTHER buffer
      if (st) *outp = hn;
      outp += OSTRIDE;
      xv = xnv;
    }
  }
  if (st) {
    out[OSTRIDE * T + (size_t)bg0 * H + j] = hn;               // h_last
    out[OSTRIDE * T + OSTRIDE + (size_t)bg0 * H + j] = c;      // c_last
  }
}

extern "C" void kernel_launch(void* const* d_in, const int* in_sizes, int n_in,
                              void* d_out, int out_size, void* d_ws, size_t ws_size,
                              hipStream_t stream) {
  (void)in_sizes; (void)n_in; (void)d_ws; (void)ws_size; (void)out_size;
  const float* x  = (const float*)d_in[0];
  const float* W  = (const float*)d_in[1];
  const float* U  = (const float*)d_in[2];
  const float* bw = (const float*)d_in[3];
  const float* bu = (const float*)d_in[4];
  float* out = (float*)d_out;

  const int grid = (B + BPW - 1) / BPW;       // 683 one-wave blocks
  lstm_wave4<<<dim3(grid), dim3(64), 0, stream>>>(x, W, U, bw, bu, out);
}